// Round 5
// baseline (246.892 us; speedup 1.0000x reference)
//
#include <hip/hip_runtime.h>
#include <hip/hip_bf16.h>

typedef unsigned short u16;
typedef unsigned int u32;
typedef __attribute__((ext_vector_type(2))) float f32x2;
typedef __attribute__((ext_vector_type(4))) float f32x4;
typedef __attribute__((ext_vector_type(4))) u16 u16x4;
typedef __attribute__((ext_vector_type(8))) u16 u16x8;
typedef __attribute__((ext_vector_type(8))) __bf16 bf16x8;

#define B_ 32
#define T_ 2048
#define MID_ 1024
#define TOPIC_ 512
#define H_ 256
#define ROWS_ 64
#define NCH_ (T_ / ROWS_)   // 32 chunks per batch

// fp32 -> bf16 RNE
static __device__ __forceinline__ u16 f2bf(float x) {
    u32 u = __float_as_uint(x);
    u = (u + 0x7FFFu + ((u >> 16) & 1u)) >> 16;
    return (u16)u;
}
static __device__ __forceinline__ float bf2f(u32 lo16) {
    return __uint_as_float(lo16 << 16);
}

// ---------------- merged prep ----------------
// blocks 0..255   : Wa row h=blk -> bf16, layout [ks=32][h=256][kk=32] (linear)
// blocks 256..287 : enc_out[b][h] = Ua_b[h] + sum_d enc[b][d]*Ua_w[h][d], b=blk-256
// block 288       : vsum = sum_h v_w[h]
__global__ __launch_bounds__(256) void k_prep(const float* __restrict__ enc,
                                              const float* __restrict__ Ua_w,
                                              const float* __restrict__ Ua_b,
                                              const float* __restrict__ Wa,
                                              const float* __restrict__ v_w,
                                              float* __restrict__ enc_out,
                                              u16* __restrict__ wa16s,
                                              float* __restrict__ vsum) {
    __shared__ float es[TOPIC_];
    const int blk = blockIdx.x, tid = threadIdx.x;
    if (blk < 256) {
        const int h = blk, k = tid * 4;
        f32x4 w = *(const f32x4*)(Wa + h * MID_ + k);
        u16x4 h4;
        h4[0] = f2bf(w[0]); h4[1] = f2bf(w[1]); h4[2] = f2bf(w[2]); h4[3] = f2bf(w[3]);
        *(u16x4*)&wa16s[(k >> 5) * (H_ * 32) + h * 32 + (k & 31)] = h4;
    } else if (blk < 288) {
        const int b = blk - 256;
        es[tid]       = enc[b * TOPIC_ + tid];
        es[tid + 256] = enc[b * TOPIC_ + 256 + tid];
        __syncthreads();
        const float* ua = Ua_w + (size_t)tid * TOPIC_;
        float s = Ua_b[tid];
        #pragma unroll 4
        for (int d = 0; d < TOPIC_; d += 4) {
            f32x4 u = *(const f32x4*)(ua + d);
            s += u[0] * es[d] + u[1] * es[d + 1] + u[2] * es[d + 2] + u[3] * es[d + 3];
        }
        enc_out[b * H_ + tid] = s;
    } else {
        if (tid < 64) {
            const int lane = tid;
            float s = v_w[lane] + v_w[lane + 64] + v_w[lane + 128] + v_w[lane + 192];
            #pragma unroll
            for (int m = 32; m; m >>= 1) s += __shfl_xor(s, m, 64);
            if (lane == 0) *vsum = s;
        }
    }
}

// ---------------- fused single-pass, barrier-free K-loop ----------------
// grid 1024 = (b:32, chunk:32), 512 threads = 8 waves.
// Wave (rg=wave&3, ch=wave>>2): 16-row x 128-col tile. A: global->regs (4-deep),
// f2bf -> MFMA operand directly. B: global->regs (depth-2 bE/bO). ch==0 waves also
// ds_write the bf16 A-frag into a swizzled LDS tile (write-only; read in wsum phase).
// NO __syncthreads in the K-loop: waves drift, counted vmcnt chains never drain.
__global__ __launch_bounds__(512, 1) void k_fused(const float* __restrict__ dec,
                                                  const int* __restrict__ masks,
                                                  const float* __restrict__ enc_out,
                                                  const float* __restrict__ v_w,
                                                  const float* __restrict__ vsum_p,
                                                  const u16* __restrict__ wa16s,
                                                  float* __restrict__ po,
                                                  float* __restrict__ pms) {
    __shared__ __attribute__((aligned(16))) u16 As[ROWS_ * MID_];  // 128 KB
    __shared__ float partc[2][ROWS_];
    __shared__ float ev[ROWS_];

    const int tid = threadIdx.x;
    const int lane = tid & 63, wave = tid >> 6;
    const int rg = wave & 3, ch = wave >> 2;
    const int rl = lane & 15, kgrp = lane >> 4;
    const int wg = blockIdx.x;
    const int b = wg >> 5, chunk = wg & (NCH_ - 1);

    // enc/v per-lane registers (8 col-subtiles of 16)
    float encr[8], vr[8];
    #pragma unroll
    for (int tc = 0; tc < 8; ++tc) {
        const int h = ch * 128 + tc * 16 + rl;
        encr[tc] = enc_out[b * H_ + h];
        vr[tc] = v_w[h];
    }

    // A: this lane's fragment source = dec[row][ks*32 + kgrp*8 .. +8)
    const int arow = rg * 16 + rl;  // local row 0..63
    const float* asrc = dec + (size_t)(b * T_ + chunk * ROWS_ + arow) * MID_ + kgrp * 8;
    char* awp = (char*)As + arow * 2048;
    const int awkey = (arow & 7) << 4;

    // B: per-tile fragment source (1 KB contiguous per tile across the wave)
    const u16* bbase = wa16s + (ch * 128 + rl) * 32 + kgrp * 8;

    f32x4 a0[2], a1[2], a2[2], a3[2];
    bf16x8 bE[8], bO[8];
    f32x4 acc[8];
    const f32x4 z = {0.f, 0.f, 0.f, 0.f};
    #pragma unroll
    for (int i = 0; i < 8; ++i) acc[i] = z;

    // ---- prologue: A(0..3), B(0), B(1) ----
    a0[0] = *(const f32x4*)(asrc);       a0[1] = *(const f32x4*)(asrc + 4);
    a1[0] = *(const f32x4*)(asrc + 32);  a1[1] = *(const f32x4*)(asrc + 36);
    a2[0] = *(const f32x4*)(asrc + 64);  a2[1] = *(const f32x4*)(asrc + 68);
    a3[0] = *(const f32x4*)(asrc + 96);  a3[1] = *(const f32x4*)(asrc + 100);
    #pragma unroll
    for (int tc = 0; tc < 8; ++tc) bE[tc] = *(const bf16x8*)(bbase + tc * 512);
    #pragma unroll
    for (int tc = 0; tc < 8; ++tc) bO[tc] = *(const bf16x8*)(bbase + 8192 + tc * 512);

    // SUB: one K-step. Uses aR (2x f32x4) and bR[8]; then reloads aR <- ks+4, bR <- ks+2.
    #define SUB(KS, AR, BR)                                                        \
        do {                                                                       \
            const int ks_ = (KS);                                                  \
            u16x8 h8_;                                                             \
            _Pragma("unroll") for (int i = 0; i < 4; ++i) {                        \
                h8_[i] = f2bf(AR[0][i]); h8_[4 + i] = f2bf(AR[1][i]);              \
            }                                                                      \
            if (ch == 0)                                                           \
                *(u16x8*)(awp + ((ks_ * 64 + kgrp * 16) ^ awkey)) = h8_;           \
            const bf16x8 af_ = __builtin_bit_cast(bf16x8, h8_);                    \
            _Pragma("unroll") for (int tc = 0; tc < 8; ++tc)                       \
                acc[tc] = __builtin_amdgcn_mfma_f32_16x16x32_bf16(af_, BR[tc],     \
                                                                  acc[tc], 0, 0, 0); \
            const int an_ = ((ks_ + 4) & 31) * 32;                                 \
            AR[0] = *(const f32x4*)(asrc + an_);                                   \
            AR[1] = *(const f32x4*)(asrc + an_ + 4);                               \
            const u16* bp_ = bbase + ((ks_ + 2) & 31) * 8192;                      \
            _Pragma("unroll") for (int tc = 0; tc < 8; ++tc)                       \
                BR[tc] = *(const bf16x8*)(bp_ + tc * 512);                         \
        } while (0)

    #pragma unroll 1
    for (int it = 0; it < 8; ++it) {
        const int ks0 = it * 4;
        SUB(ks0 + 0, a0, bE);
        SUB(ks0 + 1, a1, bO);
        SUB(ks0 + 2, a2, bE);
        SUB(ks0 + 3, a3, bO);
    }
    #undef SUB

    // ---- logits: per-lane partials over this wave's 128 cols ----
    // acc[tc][j] = C[row = rg*16 + kgrp*4 + j][col = ch*128 + tc*16 + rl]
    float part[4];
    #pragma unroll
    for (int j = 0; j < 4; ++j) {
        float p = 0.f;
        #pragma unroll
        for (int tc = 0; tc < 8; ++tc)
            p += vr[tc] * tanhf(encr[tc] + acc[tc][j]);
        part[j] = p;
    }
    #pragma unroll
    for (int m = 1; m < 16; m <<= 1)
        #pragma unroll
        for (int j = 0; j < 4; ++j)
            part[j] += __shfl_xor(part[j], m, 64);
    if (rl == 0) {
        #pragma unroll
        for (int j = 0; j < 4; ++j)
            partc[ch][rg * 16 + kgrp * 4 + j] = part[j];
    }
    __syncthreads();   // also covers all ds_writes of the As tile

    // ---- chunk softmax (64 rows = 64 lanes of wave 0) ----
    if (wave == 0) {
        const int r = lane;
        float a = partc[0][r] + partc[1][r];
        const int mk = masks[b * T_ + chunk * ROWS_ + r];
        a = mk ? a : -(*vsum_p);          // tanh(-inf) = -1 -> logit = -sum(v)
        float mx = a;
        #pragma unroll
        for (int m = 1; m < 64; m <<= 1) mx = fmaxf(mx, __shfl_xor(mx, m, 64));
        const float e = expf(a - mx);
        float s = e;
        #pragma unroll
        for (int m = 1; m < 64; m <<= 1) s += __shfl_xor(s, m, 64);
        ev[r] = e;
        if (lane == 0) { pms[wg * 2] = mx; pms[wg * 2 + 1] = s; }
    }
    __syncthreads();

    // ---- partial weighted sum from the bf16 LDS tile ----
    // element (t, c) lives at byte t*2048 + (2c ^ ((t&7)<<4)); thread owns cols 2tid,2tid+1.
    f32x2 o = {0.f, 0.f};
    const int cb = tid * 4;   // byte offset of col pair within a row
    #pragma unroll 8
    for (int t = 0; t < ROWS_; ++t) {
        const u32 h2 = *(const u32*)((const char*)As + t * 2048 + (cb ^ ((t & 7) << 4)));
        const float w = ev[t];
        o[0] += w * bf2f(h2 & 0xFFFFu);
        o[1] += w * bf2f(h2 >> 16);
    }
    *(f32x2*)&po[(size_t)wg * MID_ + tid * 2] = o;
}

// ---------------- combine: out[b][m] = sum_c w_c * o_c[m] ----------------
__global__ __launch_bounds__(256) void k_comb(const float* __restrict__ po,
                                              const float* __restrict__ pms,
                                              float* __restrict__ out) {
    __shared__ float wch[NCH_];
    const int b = blockIdx.x, tid = threadIdx.x;
    if (tid < 64) {
        const int c = tid & 31;
        const float mi = pms[(b * NCH_ + c) * 2];
        const float si = pms[(b * NCH_ + c) * 2 + 1];
        float M = mi;
        #pragma unroll
        for (int m = 1; m < 32; m <<= 1) M = fmaxf(M, __shfl_xor(M, m, 64));
        const float w = expf(mi - M);
        float D = si * w;
        #pragma unroll
        for (int m = 1; m < 32; m <<= 1) D += __shfl_xor(D, m, 64);
        if (tid < 32) wch[c] = w / D;
    }
    __syncthreads();
    #pragma unroll
    for (int i = 0; i < 4; ++i) {
        const int mcol = i * 256 + tid;
        float s = 0.f;
        for (int c = 0; c < NCH_; ++c)
            s += wch[c] * po[((size_t)b * NCH_ + c) * MID_ + mcol];
        out[b * MID_ + mcol] = s;
    }
}

extern "C" void kernel_launch(void* const* d_in, const int* in_sizes, int n_in,
                              void* d_out, int out_size, void* d_ws, size_t ws_size,
                              hipStream_t stream) {
    const float* enc   = (const float*)d_in[0];
    const float* dec   = (const float*)d_in[1];
    const int*   masks = (const int*)d_in[2];
    const float* Ua_w  = (const float*)d_in[3];
    const float* Ua_b  = (const float*)d_in[4];
    const float* Wa_w  = (const float*)d_in[5];
    const float* v_w   = (const float*)d_in[6];
    float* out = (float*)d_out;

    char* ws = (char*)d_ws;
    float* enc_out = (float*)(ws + 0);        // 32 KB
    float* vsum    = (float*)(ws + 32768);    // 4 B (padded)
    u16*   wa16s   = (u16*)(ws + 65536);      // 512 KB
    float* pms     = (float*)(ws + 589824);   // 8 KB (1024 x {max,sum}), padded
    float* po      = (float*)(ws + 606208);   // 4 MB (1024 x 1024 partial sums)

    k_prep<<<dim3(289), dim3(256), 0, stream>>>(enc, Ua_w, Ua_b, Wa_w, v_w,
                                                enc_out, wa16s, vsum);
    k_fused<<<dim3(B_ * NCH_), dim3(512), 0, stream>>>(dec, masks, enc_out, v_w, vsum,
                                                       wa16s, po, pms);
    k_comb<<<dim3(B_), dim3(256), 0, stream>>>(po, pms, out);
}

// Round 6
// 193.616 us; speedup vs baseline: 1.2752x; 1.2752x over previous
//
#include <hip/hip_runtime.h>
#include <hip/hip_bf16.h>

typedef unsigned short u16;
typedef unsigned int u32;
typedef __attribute__((ext_vector_type(2))) float f32x2;
typedef __attribute__((ext_vector_type(4))) float f32x4;
typedef __attribute__((ext_vector_type(4))) u16 u16x4;
typedef __attribute__((ext_vector_type(8))) u16 u16x8;
typedef __attribute__((ext_vector_type(8))) __bf16 bf16x8;

#define B_ 32
#define T_ 2048
#define MID_ 1024
#define TOPIC_ 512
#define H_ 256
#define ROWS_ 64
#define NCH_ (T_ / ROWS_)   // 32 chunks per batch

// fp32 -> bf16 RNE
static __device__ __forceinline__ u16 f2bf(float x) {
    u32 u = __float_as_uint(x);
    u = (u + 0x7FFFu + ((u >> 16) & 1u)) >> 16;
    return (u16)u;
}
static __device__ __forceinline__ float bf2f(u32 lo16) {
    return __uint_as_float(lo16 << 16);
}

static __device__ __forceinline__ void gl_lds16(const u16* g, u16* l) {
    __builtin_amdgcn_global_load_lds((const __attribute__((address_space(1))) void*)(const void*)g,
                                     (__attribute__((address_space(3))) void*)(void*)l,
                                     16, 0, 0);
}

// ---------------- merged prep ----------------
// blocks 0..255 : Wa row h=blk -> bf16 into layout
//   wa16s[ks:32][tt:16][kgrp:4][rl:16][j:8]  (u16 idx = ks*8192 + tt*512 + kgrp*128 + rl*8 + j)
//   where h = tt*16 + rl, k = ks*32 + kgrp*8 + j.  This makes the fused kernel's
//   global_load_lds staging a LINEAR copy and the B-frag ds_read_b128 conflict-free.
// blocks 256..287 : enc_out[b][h];  block 288 : vsum.
__global__ __launch_bounds__(256) void k_prep(const float* __restrict__ enc,
                                              const float* __restrict__ Ua_w,
                                              const float* __restrict__ Ua_b,
                                              const float* __restrict__ Wa,
                                              const float* __restrict__ v_w,
                                              float* __restrict__ enc_out,
                                              u16* __restrict__ wa16s,
                                              float* __restrict__ vsum) {
    __shared__ float es[TOPIC_];
    const int blk = blockIdx.x, tid = threadIdx.x;
    if (blk < 256) {
        const int h = blk, k = tid * 4;
        f32x4 w = *(const f32x4*)(Wa + h * MID_ + k);
        u16x4 h4;
        h4[0] = f2bf(w[0]); h4[1] = f2bf(w[1]); h4[2] = f2bf(w[2]); h4[3] = f2bf(w[3]);
        const int tt = h >> 4, rl = h & 15;
        const int ks = k >> 5, kg = (k >> 3) & 3, j = k & 7;
        *(u16x4*)&wa16s[ks * 8192 + tt * 512 + kg * 128 + rl * 8 + j] = h4;
    } else if (blk < 288) {
        const int b = blk - 256;
        es[tid]       = enc[b * TOPIC_ + tid];
        es[tid + 256] = enc[b * TOPIC_ + 256 + tid];
        __syncthreads();
        const float* ua = Ua_w + (size_t)tid * TOPIC_;
        float s = Ua_b[tid];
        #pragma unroll 4
        for (int d = 0; d < TOPIC_; d += 4) {
            f32x4 u = *(const f32x4*)(ua + d);
            s += u[0] * es[d] + u[1] * es[d + 1] + u[2] * es[d + 2] + u[3] * es[d + 3];
        }
        enc_out[b * H_ + tid] = s;
    } else {
        if (tid < 64) {
            const int lane = tid;
            float s = v_w[lane] + v_w[lane + 64] + v_w[lane + 128] + v_w[lane + 192];
            #pragma unroll
            for (int m = 32; m; m >>= 1) s += __shfl_xor(s, m, 64);
            if (lane == 0) *vsum = s;
        }
    }
}

// ---------------- fused single-pass kernel ----------------
// grid 1024 = (b:32, chunk:32), 512 threads = 8 waves (rg=wave&1, ch=wave>>1).
// Wave tile: rows rg*32..+32, cols ch*64..+64 -> acc[2][4].
// As (128 KB) = persistent bf16 dec tile, XOR-swizzled key (row&31)<<4 bytes;
//   doubles as a 32-deep K-slice multibuffer: ch==0 waves stage slice k+1
//   (global->reg->cvt->ds_write) while everyone computes slice k. Disjoint regions.
// Bb (32 KB) = ch-private double-buffered Wa slices via global_load_lds (linear).
// ONE __syncthreads per K-step. Epilogue scratch overlays dead Bb space.
__global__ __launch_bounds__(512, 1) void k_fused(const float* __restrict__ dec,
                                                  const int* __restrict__ masks,
                                                  const float* __restrict__ enc_out,
                                                  const float* __restrict__ v_w,
                                                  const float* __restrict__ vsum_p,
                                                  const u16* __restrict__ wa16s,
                                                  float* __restrict__ po,
                                                  float* __restrict__ pms) {
    __shared__ __attribute__((aligned(16))) u16 As[ROWS_ * MID_];   // 128 KB
    __shared__ __attribute__((aligned(16))) u16 Bb[8 * 2048];       // 32 KB
    float* partc = (float*)Bb;          // [4][64] overlay (epilogue only)
    float* ev    = (float*)Bb + 256;    // [64]

    const int tid = threadIdx.x;
    const int lane = tid & 63, wave = tid >> 6;
    const int rg = wave & 1, ch = wave >> 1;           // rg 0..1, ch 0..3
    const int rl = lane & 15, kgrp = lane >> 4;
    const int wg = blockIdx.x;
    const int b = wg >> 5, chunk = wg & (NCH_ - 1);
    const int grow = b * T_ + chunk * ROWS_;

    // enc/v per-lane registers (this wave's 64 cols)
    float encr[4], vr[4];
    #pragma unroll
    for (int tc = 0; tc < 4; ++tc) {
        const int h = ch * 64 + tc * 16 + rl;
        encr[tc] = enc_out[b * H_ + h];
        vr[tc] = v_w[h];
    }

    // ---- A staging (ch==0 waves): lane -> (row = rg*32 + (lane&31), half = lane>>5) ----
    const int srow = lane & 31, shalf = lane >> 5;
    const int arow = rg * 32 + srow;
    const float* astage = dec + (size_t)(grow + arow) * MID_ + shalf * 16;
    const int awbase = arow * MID_;                 // u16 units (row stride 1024 u16)
    const int awkey = (arow & 31) << 3;             // XOR key in u16 units
    f32x4 sreg[4];

    // ---- B staging: wave stages 2 x 1KB of its ch's next buffer ----
    const u16* bsrc = wa16s + ch * 2048 + rg * 1024 + lane * 8;
    const int bdst = ch * 4096 + rg * 1024;         // + buf*2048 + inst*512

    // ---- A-frag read bases ----
    const int row0 = rg * 32 + rl, row1 = row0 + 16;
    const int arb0 = row0 * MID_, ak0 = (row0 & 31) << 3;
    const int arb1 = row1 * MID_, ak1 = (row1 & 31) << 3;
    // B-frag read base (u16): (ch*2+buf)*2048 + tc*512 + kgrp*128 + rl*8
    const int brb = ch * 4096 + kgrp * 128 + rl * 8;

    f32x4 acc[2][4];
    const f32x4 z = {0.f, 0.f, 0.f, 0.f};
    #pragma unroll
    for (int i = 0; i < 2; ++i)
        #pragma unroll
        for (int j = 0; j < 4; ++j) acc[i][j] = z;

    // ---- prologue: slice 0 -> As; preload sreg <- slice 1; B(0) -> Bb buf0 ----
    if (ch == 0) {
        #pragma unroll
        for (int i = 0; i < 4; ++i) sreg[i] = *(const f32x4*)(astage + i * 4);
        u16x8 h8a, h8b;
        #pragma unroll
        for (int i = 0; i < 4; ++i) { h8a[i] = f2bf(sreg[0][i]); h8a[4 + i] = f2bf(sreg[1][i]); }
        #pragma unroll
        for (int i = 0; i < 4; ++i) { h8b[i] = f2bf(sreg[2][i]); h8b[4 + i] = f2bf(sreg[3][i]); }
        *(u16x8*)&As[awbase + ((shalf * 16) ^ awkey)] = h8a;
        *(u16x8*)&As[awbase + ((shalf * 16 + 8) ^ awkey)] = h8b;
        #pragma unroll
        for (int i = 0; i < 4; ++i) sreg[i] = *(const f32x4*)(astage + 32 + i * 4);
    }
    gl_lds16(bsrc, &Bb[bdst]);
    gl_lds16(bsrc + 512, &Bb[bdst + 512]);
    __syncthreads();

    // ---- K loop: one barrier per step ----
    #pragma unroll 2
    for (int k = 0; k < 32; ++k) {
        const int buf = k & 1;
        // (a) write slice k+1 from sreg (loaded last step -> already landed)
        if (k < 31 && ch == 0) {
            u16x8 h8a, h8b;
            #pragma unroll
            for (int i = 0; i < 4; ++i) { h8a[i] = f2bf(sreg[0][i]); h8a[4 + i] = f2bf(sreg[1][i]); }
            #pragma unroll
            for (int i = 0; i < 4; ++i) { h8b[i] = f2bf(sreg[2][i]); h8b[4 + i] = f2bf(sreg[3][i]); }
            const int ko = (k + 1) * 32 + shalf * 16;
            *(u16x8*)&As[awbase + (ko ^ awkey)] = h8a;
            *(u16x8*)&As[awbase + ((ko + 8) ^ awkey)] = h8b;
        }
        // (b) issue sreg <- A(k+2) globals (drained at this barrier; re-issued early)
        if (k < 30 && ch == 0) {
            const float* ap = astage + (k + 2) * 32;
            #pragma unroll
            for (int i = 0; i < 4; ++i) sreg[i] = *(const f32x4*)(ap + i * 4);
        }
        // (c) stage B(k+1) into the other buffer
        if (k < 31) {
            const u16* bp = bsrc + (k + 1) * 8192;
            u16* bd = &Bb[bdst + (buf ^ 1) * 2048];
            gl_lds16(bp, bd);
            gl_lds16(bp + 512, bd + 512);
        }
        // (d) compute slice k
        {
            bf16x8 af0 = *(const bf16x8*)&As[arb0 + ((k * 32 + kgrp * 8) ^ ak0)];
            bf16x8 af1 = *(const bf16x8*)&As[arb1 + ((k * 32 + kgrp * 8) ^ ak1)];
            const int bb = brb + buf * 2048;
            #pragma unroll
            for (int tc = 0; tc < 4; ++tc) {
                bf16x8 bf = *(const bf16x8*)&Bb[bb + tc * 512];
                acc[0][tc] = __builtin_amdgcn_mfma_f32_16x16x32_bf16(af0, bf, acc[0][tc], 0, 0, 0);
                acc[1][tc] = __builtin_amdgcn_mfma_f32_16x16x32_bf16(af1, bf, acc[1][tc], 0, 0, 0);
            }
        }
        __syncthreads();
    }

    // ---- logits partials (Bb is dead -> partc/ev overlay) ----
    // acc[tf][tc][j] = C[row = rg*32 + tf*16 + kgrp*4 + j][col = ch*64 + tc*16 + rl]
    float part[2][4];
    #pragma unroll
    for (int tf = 0; tf < 2; ++tf)
        #pragma unroll
        for (int j = 0; j < 4; ++j) {
            float p = 0.f;
            #pragma unroll
            for (int tc = 0; tc < 4; ++tc)
                p += vr[tc] * tanhf(encr[tc] + acc[tf][tc][j]);
            part[tf][j] = p;
        }
    #pragma unroll
    for (int m = 1; m < 16; m <<= 1)
        #pragma unroll
        for (int tf = 0; tf < 2; ++tf)
            #pragma unroll
            for (int j = 0; j < 4; ++j)
                part[tf][j] += __shfl_xor(part[tf][j], m, 64);
    if (rl == 0) {
        #pragma unroll
        for (int tf = 0; tf < 2; ++tf)
            #pragma unroll
            for (int j = 0; j < 4; ++j)
                partc[ch * 64 + rg * 32 + tf * 16 + kgrp * 4 + j] = part[tf][j];
    }
    __syncthreads();

    // ---- chunk softmax (64 rows = 64 lanes of wave 0) ----
    if (wave == 0) {
        const int r = lane;
        float a = partc[r] + partc[64 + r] + partc[128 + r] + partc[192 + r];
        const int mk = masks[grow + r];
        a = mk ? a : -(*vsum_p);          // tanh(-inf) = -1 -> logit = -sum(v)
        float mx = a;
        #pragma unroll
        for (int m = 1; m < 64; m <<= 1) mx = fmaxf(mx, __shfl_xor(mx, m, 64));
        const float e = expf(a - mx);
        float s = e;
        #pragma unroll
        for (int m = 1; m < 64; m <<= 1) s += __shfl_xor(s, m, 64);
        ev[r] = e;
        if (lane == 0) { pms[wg * 2] = mx; pms[wg * 2 + 1] = s; }
    }
    __syncthreads();

    // ---- partial weighted sum from the bf16 As tile ----
    f32x2 o = {0.f, 0.f};
    const int cu = tid * 2;                 // u16 offset of col pair within a row
    #pragma unroll 8
    for (int t = 0; t < ROWS_; ++t) {
        const u32 h2 = *(const u32*)&As[t * MID_ + (cu ^ ((t & 31) << 3))];
        const float w = ev[t];
        o[0] += w * bf2f(h2 & 0xFFFFu);
        o[1] += w * bf2f(h2 >> 16);
    }
    *(f32x2*)&po[(size_t)wg * MID_ + cu] = o;
}

// ---------------- combine: out[b][m] = sum_c w_c * o_c[m] ----------------
__global__ __launch_bounds__(256) void k_comb(const float* __restrict__ po,
                                              const float* __restrict__ pms,
                                              float* __restrict__ out) {
    __shared__ float wch[NCH_];
    const int b = blockIdx.x, tid = threadIdx.x;
    if (tid < 64) {
        const int c = tid & 31;
        const float mi = pms[(b * NCH_ + c) * 2];
        const float si = pms[(b * NCH_ + c) * 2 + 1];
        float M = mi;
        #pragma unroll
        for (int m = 1; m < 32; m <<= 1) M = fmaxf(M, __shfl_xor(M, m, 64));
        const float w = expf(mi - M);
        float D = si * w;
        #pragma unroll
        for (int m = 1; m < 32; m <<= 1) D += __shfl_xor(D, m, 64);
        if (tid < 32) wch[c] = w / D;
    }
    __syncthreads();
    #pragma unroll
    for (int i = 0; i < 4; ++i) {
        const int mcol = i * 256 + tid;
        float s = 0.f;
        for (int c = 0; c < NCH_; ++c)
            s += wch[c] * po[((size_t)b * NCH_ + c) * MID_ + mcol];
        out[b * MID_ + mcol] = s;
    }
}

extern "C" void kernel_launch(void* const* d_in, const int* in_sizes, int n_in,
                              void* d_out, int out_size, void* d_ws, size_t ws_size,
                              hipStream_t stream) {
    const float* enc   = (const float*)d_in[0];
    const float* dec   = (const float*)d_in[1];
    const int*   masks = (const int*)d_in[2];
    const float* Ua_w  = (const float*)d_in[3];
    const float* Ua_b  = (const float*)d_in[4];
    const float* Wa_w  = (const float*)d_in[5];
    const float* v_w   = (const float*)d_in[6];
    float* out = (float*)d_out;

    char* ws = (char*)d_ws;
    float* enc_out = (float*)(ws + 0);        // 32 KB
    float* vsum    = (float*)(ws + 32768);    // 4 B (padded)
    u16*   wa16s   = (u16*)(ws + 65536);      // 512 KB
    float* pms     = (float*)(ws + 589824);   // 8 KB (1024 x {max,sum}), padded
    float* po      = (float*)(ws + 606208);   // 4 MB (1024 x 1024 partial sums)

    k_prep<<<dim3(289), dim3(256), 0, stream>>>(enc, Ua_w, Ua_b, Wa_w, v_w,
                                                enc_out, wa16s, vsum);
    k_fused<<<dim3(B_ * NCH_), dim3(512), 0, stream>>>(dec, masks, enc_out, v_w, vsum,
                                                       wa16s, po, pms);
    k_comb<<<dim3(B_), dim3(256), 0, stream>>>(po, pms, out);
}

// Round 7
// 144.639 us; speedup vs baseline: 1.7070x; 1.3386x over previous
//
#include <hip/hip_runtime.h>
#include <hip/hip_bf16.h>

typedef unsigned short u16;
typedef unsigned int u32;
typedef __attribute__((ext_vector_type(2))) float f32x2;
typedef __attribute__((ext_vector_type(4))) float f32x4;
typedef __attribute__((ext_vector_type(4))) u16 u16x4;
typedef __attribute__((ext_vector_type(8))) u16 u16x8;
typedef __attribute__((ext_vector_type(8))) __bf16 bf16x8;

#define B_ 32
#define T_ 2048
#define MID_ 1024
#define TOPIC_ 512
#define H_ 256
#define ROWS_ 32
#define NCH_ (T_ / ROWS_)   // 64 chunks per batch

// fp32 -> bf16 RNE
static __device__ __forceinline__ u16 f2bf(float x) {
    u32 u = __float_as_uint(x);
    u = (u + 0x7FFFu + ((u >> 16) & 1u)) >> 16;
    return (u16)u;
}
static __device__ __forceinline__ float bf2f(u32 lo16) {
    return __uint_as_float(lo16 << 16);
}

// ---------------- merged prep ----------------
// blocks 0..255 : Wa row h=blk -> bf16 into layout
//   wa16s[ks:32][tt:16][kgrp:4][rl:16][j:8]  (u16 idx = ks*8192 + tt*512 + kgrp*128 + rl*8 + j)
//   where h = tt*16 + rl, k = ks*32 + kgrp*8 + j.  B-frag loads in k_fused become
//   1KB-contiguous per (tile, k-slice) -> perfectly coalesced.
// blocks 256..287 : enc_out[b][h];  block 288 : vsum.
__global__ __launch_bounds__(256) void k_prep(const float* __restrict__ enc,
                                              const float* __restrict__ Ua_w,
                                              const float* __restrict__ Ua_b,
                                              const float* __restrict__ Wa,
                                              const float* __restrict__ v_w,
                                              float* __restrict__ enc_out,
                                              u16* __restrict__ wa16s,
                                              float* __restrict__ vsum) {
    __shared__ float es[TOPIC_];
    const int blk = blockIdx.x, tid = threadIdx.x;
    if (blk < 256) {
        const int h = blk, k = tid * 4;
        f32x4 w = *(const f32x4*)(Wa + h * MID_ + k);
        u16x4 h4;
        h4[0] = f2bf(w[0]); h4[1] = f2bf(w[1]); h4[2] = f2bf(w[2]); h4[3] = f2bf(w[3]);
        const int tt = h >> 4, rl = h & 15;
        const int ks = k >> 5, kg = (k >> 3) & 3, j = k & 7;
        *(u16x4*)&wa16s[ks * 8192 + tt * 512 + kg * 128 + rl * 8 + j] = h4;
    } else if (blk < 288) {
        const int b = blk - 256;
        es[tid]       = enc[b * TOPIC_ + tid];
        es[tid + 256] = enc[b * TOPIC_ + 256 + tid];
        __syncthreads();
        const float* ua = Ua_w + (size_t)tid * TOPIC_;
        float s = Ua_b[tid];
        #pragma unroll 4
        for (int d = 0; d < TOPIC_; d += 4) {
            f32x4 u = *(const f32x4*)(ua + d);
            s += u[0] * es[d] + u[1] * es[d + 1] + u[2] * es[d + 2] + u[3] * es[d + 3];
        }
        enc_out[b * H_ + tid] = s;
    } else {
        if (tid < 64) {
            const int lane = tid;
            float s = v_w[lane] + v_w[lane + 64] + v_w[lane + 128] + v_w[lane + 192];
            #pragma unroll
            for (int m = 32; m; m >>= 1) s += __shfl_xor(s, m, 64);
            if (lane == 0) *vsum = s;
        }
    }
}

// ---------------- fused single-pass kernel ----------------
// grid 2048 = (b:32, chunk:64), 512 threads = 8 waves, 2 WGs/CU (LDS ~65 KB).
// Phase 1: stage dec chunk (32x1024 fp32) -> bf16 As, XOR-swizzled; ONE barrier.
// Phase 2: barrier-free GEMM. Wave w owns ALL 32 rows x cols w*32..w*32+31
//          (zero B redundancy: 16 KB/step/WG). A-frags via ds_read_b128 (0-conflict
//          swizzle, counter-verified round 6); B global->reg double-buffered.
// Phase 3: logits reduce + chunk softmax + weighted sum from the LDS bf16 tile.
__global__ __launch_bounds__(512, 4) void k_fused(const float* __restrict__ dec,
                                                  const int* __restrict__ masks,
                                                  const float* __restrict__ enc_out,
                                                  const float* __restrict__ v_w,
                                                  const float* __restrict__ vsum_p,
                                                  const u16* __restrict__ wa16s,
                                                  float* __restrict__ po,
                                                  float* __restrict__ pms) {
    __shared__ __attribute__((aligned(16))) u16 As[ROWS_ * MID_];   // 64 KB
    __shared__ float partc[8][ROWS_];
    __shared__ float ev[ROWS_];

    const int tid = threadIdx.x;
    const int lane = tid & 63, wave = tid >> 6;
    const int rl = lane & 15, kgrp = lane >> 4;
    const int wg = blockIdx.x;
    const int b = wg >> 6, chunk = wg & (NCH_ - 1);
    const int grow = b * T_ + chunk * ROWS_;

    // enc/v per-lane registers (this wave's 32 cols = 2 col-tiles)
    float encr[2], vr[2];
    #pragma unroll
    for (int ct = 0; ct < 2; ++ct) {
        const int h = wave * 32 + ct * 16 + rl;
        encr[ct] = enc_out[b * H_ + h];
        vr[ct] = v_w[h];
    }

    // ---- phase 1: stage dec -> As (bf16, swizzled). granule g = 8 cols;
    // thread handles g = tid + i*512, i=0..7 (row = g>>7, colg = g&127).
    #pragma unroll
    for (int batch = 0; batch < 2; ++batch) {
        f32x4 r[8];
        #pragma unroll
        for (int i = 0; i < 4; ++i) {
            const int g = tid + (batch * 4 + i) * 512;
            const int row = g >> 7, colg = g & 127;
            const float* sp = dec + (size_t)(grow + row) * MID_ + colg * 8;
            r[2 * i]     = *(const f32x4*)(sp);
            r[2 * i + 1] = *(const f32x4*)(sp + 4);
        }
        #pragma unroll
        for (int i = 0; i < 4; ++i) {
            const int g = tid + (batch * 4 + i) * 512;
            const int row = g >> 7, colg = g & 127;
            u16x8 h8;
            #pragma unroll
            for (int e = 0; e < 4; ++e) {
                h8[e]     = f2bf(r[2 * i][e]);
                h8[4 + e] = f2bf(r[2 * i + 1][e]);
            }
            *(u16x8*)&As[row * MID_ + ((colg * 8) ^ (row << 3))] = h8;
        }
    }
    __syncthreads();

    // ---- phase 2: barrier-free K-loop ----
    const u16* bb = wa16s + wave * 1024 + kgrp * 128 + rl * 8;  // +ct*512 +ks*8192
    const int ar0 = rl * MID_,        k0 = rl << 3;
    const int ar1 = (16 + rl) * MID_, k1 = (16 + rl) << 3;

    f32x4 acc[2][2];
    const f32x4 z = {0.f, 0.f, 0.f, 0.f};
    acc[0][0] = z; acc[0][1] = z; acc[1][0] = z; acc[1][1] = z;

    bf16x8 b0[2], b1[2];
    b0[0] = *(const bf16x8*)(bb);
    b0[1] = *(const bf16x8*)(bb + 512);
    b1[0] = *(const bf16x8*)(bb + 8192);
    b1[1] = *(const bf16x8*)(bb + 8192 + 512);

    #pragma unroll 1
    for (int ks = 0; ks < 32; ks += 2) {
        {   // compute slice ks with b0
            const int ko = ks * 32 + kgrp * 8;
            bf16x8 af0 = *(const bf16x8*)&As[ar0 + (ko ^ k0)];
            bf16x8 af1 = *(const bf16x8*)&As[ar1 + (ko ^ k1)];
            acc[0][0] = __builtin_amdgcn_mfma_f32_16x16x32_bf16(af0, b0[0], acc[0][0], 0, 0, 0);
            acc[1][0] = __builtin_amdgcn_mfma_f32_16x16x32_bf16(af1, b0[0], acc[1][0], 0, 0, 0);
            acc[0][1] = __builtin_amdgcn_mfma_f32_16x16x32_bf16(af0, b0[1], acc[0][1], 0, 0, 0);
            acc[1][1] = __builtin_amdgcn_mfma_f32_16x16x32_bf16(af1, b0[1], acc[1][1], 0, 0, 0);
        }
        {   // prefetch B(ks+2) into b0
            const u16* bp = bb + ((ks + 2) & 31) * 8192;
            b0[0] = *(const bf16x8*)(bp);
            b0[1] = *(const bf16x8*)(bp + 512);
        }
        {   // compute slice ks+1 with b1
            const int ko = (ks + 1) * 32 + kgrp * 8;
            bf16x8 af0 = *(const bf16x8*)&As[ar0 + (ko ^ k0)];
            bf16x8 af1 = *(const bf16x8*)&As[ar1 + (ko ^ k1)];
            acc[0][0] = __builtin_amdgcn_mfma_f32_16x16x32_bf16(af0, b1[0], acc[0][0], 0, 0, 0);
            acc[1][0] = __builtin_amdgcn_mfma_f32_16x16x32_bf16(af1, b1[0], acc[1][0], 0, 0, 0);
            acc[0][1] = __builtin_amdgcn_mfma_f32_16x16x32_bf16(af0, b1[1], acc[0][1], 0, 0, 0);
            acc[1][1] = __builtin_amdgcn_mfma_f32_16x16x32_bf16(af1, b1[1], acc[1][1], 0, 0, 0);
        }
        {   // prefetch B(ks+3) into b1
            const u16* bp = bb + ((ks + 3) & 31) * 8192;
            b1[0] = *(const bf16x8*)(bp);
            b1[1] = *(const bf16x8*)(bp + 512);
        }
    }

    // ---- phase 3a: logits partials ----
    // acc[rt][ct][j] = C[row = rt*16 + kgrp*4 + j][col = wave*32 + ct*16 + rl]
    float part[2][4];
    #pragma unroll
    for (int rt = 0; rt < 2; ++rt)
        #pragma unroll
        for (int j = 0; j < 4; ++j) {
            float p = 0.f;
            #pragma unroll
            for (int ct = 0; ct < 2; ++ct)
                p += vr[ct] * tanhf(encr[ct] + acc[rt][ct][j]);
            part[rt][j] = p;
        }
    #pragma unroll
    for (int m = 1; m < 16; m <<= 1)
        #pragma unroll
        for (int rt = 0; rt < 2; ++rt)
            #pragma unroll
            for (int j = 0; j < 4; ++j)
                part[rt][j] += __shfl_xor(part[rt][j], m, 64);
    if (rl == 0) {
        #pragma unroll
        for (int rt = 0; rt < 2; ++rt)
            #pragma unroll
            for (int j = 0; j < 4; ++j)
                partc[wave][rt * 16 + kgrp * 4 + j] = part[rt][j];
    }
    __syncthreads();

    // ---- phase 3b: chunk softmax (32 rows; wave 0, lanes duplicate 2x) ----
    if (wave == 0) {
        const int r = lane & 31;
        float a = 0.f;
        #pragma unroll
        for (int w = 0; w < 8; ++w) a += partc[w][r];
        const int mk = masks[grow + r];
        a = mk ? a : -(*vsum_p);          // tanh(-inf) = -1 -> logit = -sum(v)
        float mx = a;
        #pragma unroll
        for (int m = 1; m < 32; m <<= 1) mx = fmaxf(mx, __shfl_xor(mx, m, 64));
        const float e = expf(a - mx);
        float s = e;
        #pragma unroll
        for (int m = 1; m < 32; m <<= 1) s += __shfl_xor(s, m, 64);
        if (lane < 32) ev[r] = e;
        if (lane == 0) { pms[wg * 2] = mx; pms[wg * 2 + 1] = s; }
    }
    __syncthreads();

    // ---- phase 3c: partial weighted sum from the bf16 As tile ----
    f32x2 o = {0.f, 0.f};
    const int cu = tid * 2;                 // u16 offset of col pair within a row
    #pragma unroll 8
    for (int t = 0; t < ROWS_; ++t) {
        const u32 h2 = *(const u32*)&As[t * MID_ + (cu ^ (t << 3))];
        const float w = ev[t];
        o[0] += w * bf2f(h2 & 0xFFFFu);
        o[1] += w * bf2f(h2 >> 16);
    }
    *(f32x2*)&po[(size_t)wg * MID_ + cu] = o;
}

// ---------------- combine: out[b][m] = sum_c w_c * o_c[m] ----------------
__global__ __launch_bounds__(256) void k_comb(const float* __restrict__ po,
                                              const float* __restrict__ pms,
                                              float* __restrict__ out) {
    __shared__ float wch[NCH_];
    const int b = blockIdx.x, tid = threadIdx.x;
    if (tid < 64) {
        const float mi = pms[(b * NCH_ + tid) * 2];
        const float si = pms[(b * NCH_ + tid) * 2 + 1];
        float M = mi;
        #pragma unroll
        for (int m = 1; m < 64; m <<= 1) M = fmaxf(M, __shfl_xor(M, m, 64));
        const float w = expf(mi - M);
        float D = si * w;
        #pragma unroll
        for (int m = 1; m < 64; m <<= 1) D += __shfl_xor(D, m, 64);
        wch[tid] = w / D;
    }
    __syncthreads();
    #pragma unroll
    for (int i = 0; i < 4; ++i) {
        const int mcol = i * 256 + tid;
        float s = 0.f;
        for (int c = 0; c < NCH_; ++c)
            s += wch[c] * po[((size_t)b * NCH_ + c) * MID_ + mcol];
        out[b * MID_ + mcol] = s;
    }
}

extern "C" void kernel_launch(void* const* d_in, const int* in_sizes, int n_in,
                              void* d_out, int out_size, void* d_ws, size_t ws_size,
                              hipStream_t stream) {
    const float* enc   = (const float*)d_in[0];
    const float* dec   = (const float*)d_in[1];
    const int*   masks = (const int*)d_in[2];
    const float* Ua_w  = (const float*)d_in[3];
    const float* Ua_b  = (const float*)d_in[4];
    const float* Wa_w  = (const float*)d_in[5];
    const float* v_w   = (const float*)d_in[6];
    float* out = (float*)d_out;

    char* ws = (char*)d_ws;
    float* enc_out = (float*)(ws + 0);        // 32 KB
    float* vsum    = (float*)(ws + 32768);    // 4 B (padded)
    u16*   wa16s   = (u16*)(ws + 65536);      // 512 KB
    float* pms     = (float*)(ws + 589824);   // 16 KB (2048 x {max,sum})
    float* po      = (float*)(ws + 606208);   // 8 MB  (2048 x 1024 partial sums)

    k_prep<<<dim3(289), dim3(256), 0, stream>>>(enc, Ua_w, Ua_b, Wa_w, v_w,
                                                enc_out, wa16s, vsum);
    k_fused<<<dim3(B_ * NCH_), dim3(512), 0, stream>>>(dec, masks, enc_out, v_w, vsum,
                                                       wa16s, po, pms);
    k_comb<<<dim3(B_), dim3(256), 0, stream>>>(po, pms, out);
}

// Round 8
// 133.107 us; speedup vs baseline: 1.8548x; 1.0866x over previous
//
#include <hip/hip_runtime.h>
#include <hip/hip_bf16.h>

typedef unsigned short u16;
typedef unsigned int u32;
typedef __attribute__((ext_vector_type(2))) float f32x2;
typedef __attribute__((ext_vector_type(4))) float f32x4;
typedef __attribute__((ext_vector_type(4))) u16 u16x4;
typedef __attribute__((ext_vector_type(8))) u16 u16x8;
typedef __attribute__((ext_vector_type(8))) __bf16 bf16x8;

#define B_ 32
#define T_ 2048
#define MID_ 1024
#define TOPIC_ 512
#define H_ 256
#define ROWS_ 32
#define NCH_ (T_ / ROWS_)   // 64 chunks per batch

// fp32 -> bf16 RNE
static __device__ __forceinline__ u16 f2bf(float x) {
    u32 u = __float_as_uint(x);
    u = (u + 0x7FFFu + ((u >> 16) & 1u)) >> 16;
    return (u16)u;
}
static __device__ __forceinline__ float bf2f(u32 lo16) {
    return __uint_as_float(lo16 << 16);
}

// ---------------- merged prep ----------------
// blocks 0..255 : Wa row h=blk -> bf16 into layout
//   wa16s[ks:32][tt:16][kgrp:4][rl:16][j:8]  (u16 idx = ks*8192 + tt*512 + kgrp*128 + rl*8 + j)
//   where h = tt*16 + rl, k = ks*32 + kgrp*8 + j.  B-frag loads in k_fused become
//   1KB-contiguous per (tile, k-slice) -> perfectly coalesced.
// blocks 256..287 : enc_out[b][h];  block 288 : vsum.
__global__ __launch_bounds__(256) void k_prep(const float* __restrict__ enc,
                                              const float* __restrict__ Ua_w,
                                              const float* __restrict__ Ua_b,
                                              const float* __restrict__ Wa,
                                              const float* __restrict__ v_w,
                                              float* __restrict__ enc_out,
                                              u16* __restrict__ wa16s,
                                              float* __restrict__ vsum) {
    __shared__ float es[TOPIC_];
    const int blk = blockIdx.x, tid = threadIdx.x;
    if (blk < 256) {
        const int h = blk, k = tid * 4;
        f32x4 w = *(const f32x4*)(Wa + h * MID_ + k);
        u16x4 h4;
        h4[0] = f2bf(w[0]); h4[1] = f2bf(w[1]); h4[2] = f2bf(w[2]); h4[3] = f2bf(w[3]);
        const int tt = h >> 4, rl = h & 15;
        const int ks = k >> 5, kg = (k >> 3) & 3, j = k & 7;
        *(u16x4*)&wa16s[ks * 8192 + tt * 512 + kg * 128 + rl * 8 + j] = h4;
    } else if (blk < 288) {
        const int b = blk - 256;
        es[tid]       = enc[b * TOPIC_ + tid];
        es[tid + 256] = enc[b * TOPIC_ + 256 + tid];
        __syncthreads();
        const float* ua = Ua_w + (size_t)tid * TOPIC_;
        float s = Ua_b[tid];
        #pragma unroll 4
        for (int d = 0; d < TOPIC_; d += 4) {
            f32x4 u = *(const f32x4*)(ua + d);
            s += u[0] * es[d] + u[1] * es[d + 1] + u[2] * es[d + 2] + u[3] * es[d + 3];
        }
        enc_out[b * H_ + tid] = s;
    } else {
        if (tid < 64) {
            const int lane = tid;
            float s = v_w[lane] + v_w[lane + 64] + v_w[lane + 128] + v_w[lane + 192];
            #pragma unroll
            for (int m = 32; m; m >>= 1) s += __shfl_xor(s, m, 64);
            if (lane == 0) *vsum = s;
        }
    }
}

// ---------------- fused single-pass kernel ----------------
// grid 2048 = (b:32, chunk:64), 512 threads = 8 waves, 2 WGs/CU (LDS ~65 KB).
// Phase 1: stage dec chunk (32x1024 fp32) -> bf16 As, XOR-swizzled; ONE barrier.
// Phase 2: barrier-free fully-unrolled K-loop. Wave w owns all 32 rows x cols
//          w*32..+32 (zero B redundancy). B: global->reg ring of 4 slices (static
//          indices); A-frags ds_read_b128 double-buffered (0-conflict swizzle).
//          Per-wave rotated K-order (start slice 4*wave) spreads L2 traffic.
// Phase 3: logits reduce + chunk softmax + weighted sum from the LDS bf16 tile.
__global__ __launch_bounds__(512, 4) void k_fused(const float* __restrict__ dec,
                                                  const int* __restrict__ masks,
                                                  const float* __restrict__ enc_out,
                                                  const float* __restrict__ v_w,
                                                  const float* __restrict__ vsum_p,
                                                  const u16* __restrict__ wa16s,
                                                  float* __restrict__ po,
                                                  float* __restrict__ pms) {
    __shared__ __attribute__((aligned(16))) u16 As[ROWS_ * MID_];   // 64 KB
    __shared__ float partc[8][ROWS_];
    __shared__ float ev[ROWS_];

    const int tid = threadIdx.x;
    const int lane = tid & 63, wave = tid >> 6;
    const int rl = lane & 15, kgrp = lane >> 4;
    const int wg = blockIdx.x;
    const int b = wg >> 6, chunk = wg & (NCH_ - 1);
    const int grow = b * T_ + chunk * ROWS_;

    // enc/v per-lane registers (this wave's 32 cols = 2 col-tiles)
    float encr[2], vr[2];
    #pragma unroll
    for (int ct = 0; ct < 2; ++ct) {
        const int h = wave * 32 + ct * 16 + rl;
        encr[ct] = enc_out[b * H_ + h];
        vr[ct] = v_w[h];
    }

    // ---- phase 1: stage dec -> As (bf16, swizzled). granule g = 8 cols;
    // thread handles g = tid + i*512, i=0..7 (row = g>>7, colg = g&127).
    #pragma unroll
    for (int batch = 0; batch < 2; ++batch) {
        f32x4 r[8];
        #pragma unroll
        for (int i = 0; i < 4; ++i) {
            const int g = tid + (batch * 4 + i) * 512;
            const int row = g >> 7, colg = g & 127;
            const float* sp = dec + (size_t)(grow + row) * MID_ + colg * 8;
            r[2 * i]     = *(const f32x4*)(sp);
            r[2 * i + 1] = *(const f32x4*)(sp + 4);
        }
        #pragma unroll
        for (int i = 0; i < 4; ++i) {
            const int g = tid + (batch * 4 + i) * 512;
            const int row = g >> 7, colg = g & 127;
            u16x8 h8;
            #pragma unroll
            for (int e = 0; e < 4; ++e) {
                h8[e]     = f2bf(r[2 * i][e]);
                h8[4 + e] = f2bf(r[2 * i + 1][e]);
            }
            *(u16x8*)&As[row * MID_ + ((colg * 8) ^ (row << 3))] = h8;
        }
    }
    __syncthreads();

    // ---- phase 2: fully-unrolled barrier-free K-loop ----
    const u16* bb = wa16s + wave * 1024 + kgrp * 128 + rl * 8;  // +ct*512 +ks*8192
    const int ar0 = rl * MID_,        k0 = rl << 3;
    const int ar1 = (16 + rl) * MID_, k1 = (16 + rl) << 3;
    const int kstart = wave * 4;                 // per-wave rotated K order

    f32x4 acc[2][2];
    const f32x4 z = {0.f, 0.f, 0.f, 0.f};
    acc[0][0] = z; acc[0][1] = z; acc[1][0] = z; acc[1][1] = z;

    // B ring (4 slices deep), A-frag double buffer
    bf16x8 br0[2], br1[2], br2[2], br3[2];
    {
        const int s0 = kstart, s1 = (kstart + 1) & 31;
        const int s2 = (kstart + 2) & 31, s3 = (kstart + 3) & 31;
        br0[0] = *(const bf16x8*)(bb + s0 * 8192);
        br0[1] = *(const bf16x8*)(bb + s0 * 8192 + 512);
        br1[0] = *(const bf16x8*)(bb + s1 * 8192);
        br1[1] = *(const bf16x8*)(bb + s1 * 8192 + 512);
        br2[0] = *(const bf16x8*)(bb + s2 * 8192);
        br2[1] = *(const bf16x8*)(bb + s2 * 8192 + 512);
        br3[0] = *(const bf16x8*)(bb + s3 * 8192);
        br3[1] = *(const bf16x8*)(bb + s3 * 8192 + 512);
    }
    bf16x8 afc0 = *(const bf16x8*)&As[ar0 + ((kstart * 32 + kgrp * 8) ^ k0)];
    bf16x8 afc1 = *(const bf16x8*)&As[ar1 + ((kstart * 32 + kgrp * 8) ^ k1)];

    #pragma unroll
    for (int i = 0; i < 32; ++i) {
        // next-step A frags (issued before this step's MFMAs)
        bf16x8 an0 = afc0, an1 = afc1;
        if (i < 31) {
            const int ksn = (kstart + i + 1) & 31;
            an0 = *(const bf16x8*)&As[ar0 + ((ksn * 32 + kgrp * 8) ^ k0)];
            an1 = *(const bf16x8*)&As[ar1 + ((ksn * 32 + kgrp * 8) ^ k1)];
        }
        // MFMAs with the static ring slot (i compile-time after unroll)
        {
            bf16x8* brc = ((i & 3) == 0) ? br0 : ((i & 3) == 1) ? br1
                         : ((i & 3) == 2) ? br2 : br3;
            acc[0][0] = __builtin_amdgcn_mfma_f32_16x16x32_bf16(afc0, brc[0], acc[0][0], 0, 0, 0);
            acc[1][0] = __builtin_amdgcn_mfma_f32_16x16x32_bf16(afc1, brc[0], acc[1][0], 0, 0, 0);
            acc[0][1] = __builtin_amdgcn_mfma_f32_16x16x32_bf16(afc0, brc[1], acc[0][1], 0, 0, 0);
            acc[1][1] = __builtin_amdgcn_mfma_f32_16x16x32_bf16(afc1, brc[1], acc[1][1], 0, 0, 0);
            // refill this slot with slice i+4
            if (i < 28) {
                const int ksp = (kstart + i + 4) & 31;
                brc[0] = *(const bf16x8*)(bb + ksp * 8192);
                brc[1] = *(const bf16x8*)(bb + ksp * 8192 + 512);
            }
        }
        afc0 = an0; afc1 = an1;
    }

    // ---- phase 3a: logits partials ----
    // acc[rt][ct][j] = C[row = rt*16 + kgrp*4 + j][col = wave*32 + ct*16 + rl]
    float part[2][4];
    #pragma unroll
    for (int rt = 0; rt < 2; ++rt)
        #pragma unroll
        for (int j = 0; j < 4; ++j) {
            float p = 0.f;
            #pragma unroll
            for (int ct = 0; ct < 2; ++ct)
                p += vr[ct] * tanhf(encr[ct] + acc[rt][ct][j]);
            part[rt][j] = p;
        }
    #pragma unroll
    for (int m = 1; m < 16; m <<= 1)
        #pragma unroll
        for (int rt = 0; rt < 2; ++rt)
            #pragma unroll
            for (int j = 0; j < 4; ++j)
                part[rt][j] += __shfl_xor(part[rt][j], m, 64);
    if (rl == 0) {
        #pragma unroll
        for (int rt = 0; rt < 2; ++rt)
            #pragma unroll
            for (int j = 0; j < 4; ++j)
                partc[wave][rt * 16 + kgrp * 4 + j] = part[rt][j];
    }
    __syncthreads();

    // ---- phase 3b: chunk softmax (32 rows; wave 0, lanes duplicate 2x) ----
    if (wave == 0) {
        const int r = lane & 31;
        float a = 0.f;
        #pragma unroll
        for (int w = 0; w < 8; ++w) a += partc[w][r];
        const int mk = masks[grow + r];
        a = mk ? a : -(*vsum_p);          // tanh(-inf) = -1 -> logit = -sum(v)
        float mx = a;
        #pragma unroll
        for (int m = 1; m < 32; m <<= 1) mx = fmaxf(mx, __shfl_xor(mx, m, 64));
        const float e = expf(a - mx);
        float s = e;
        #pragma unroll
        for (int m = 1; m < 32; m <<= 1) s += __shfl_xor(s, m, 64);
        if (lane < 32) ev[r] = e;
        if (lane == 0) { pms[wg * 2] = mx; pms[wg * 2 + 1] = s; }
    }
    __syncthreads();

    // ---- phase 3c: partial weighted sum from the bf16 As tile ----
    f32x2 o = {0.f, 0.f};
    const int cu = tid * 2;                 // u16 offset of col pair within a row
    #pragma unroll
    for (int t = 0; t < ROWS_; ++t) {
        const u32 h2 = *(const u32*)&As[t * MID_ + (cu ^ (t << 3))];
        const float w = ev[t];
        o[0] += w * bf2f(h2 & 0xFFFFu);
        o[1] += w * bf2f(h2 >> 16);
    }
    *(f32x2*)&po[(size_t)wg * MID_ + cu] = o;
}

// ---------------- combine: out[b][m] = sum_c w_c * o_c[m] ----------------
__global__ __launch_bounds__(256) void k_comb(const float* __restrict__ po,
                                              const float* __restrict__ pms,
                                              float* __restrict__ out) {
    __shared__ float wch[NCH_];
    const int b = blockIdx.x, tid = threadIdx.x;
    if (tid < 64) {
        const float mi = pms[(b * NCH_ + tid) * 2];
        const float si = pms[(b * NCH_ + tid) * 2 + 1];
        float M = mi;
        #pragma unroll
        for (int m = 1; m < 64; m <<= 1) M = fmaxf(M, __shfl_xor(M, m, 64));
        const float w = expf(mi - M);
        float D = si * w;
        #pragma unroll
        for (int m = 1; m < 64; m <<= 1) D += __shfl_xor(D, m, 64);
        wch[tid] = w / D;
    }
    __syncthreads();
    #pragma unroll
    for (int i = 0; i < 4; ++i) {
        const int mcol = i * 256 + tid;
        float s = 0.f;
        for (int c = 0; c < NCH_; ++c)
            s += wch[c] * po[((size_t)b * NCH_ + c) * MID_ + mcol];
        out[b * MID_ + mcol] = s;
    }
}

extern "C" void kernel_launch(void* const* d_in, const int* in_sizes, int n_in,
                              void* d_out, int out_size, void* d_ws, size_t ws_size,
                              hipStream_t stream) {
    const float* enc   = (const float*)d_in[0];
    const float* dec   = (const float*)d_in[1];
    const int*   masks = (const int*)d_in[2];
    const float* Ua_w  = (const float*)d_in[3];
    const float* Ua_b  = (const float*)d_in[4];
    const float* Wa_w  = (const float*)d_in[5];
    const float* v_w   = (const float*)d_in[6];
    float* out = (float*)d_out;

    char* ws = (char*)d_ws;
    float* enc_out = (float*)(ws + 0);        // 32 KB
    float* vsum    = (float*)(ws + 32768);    // 4 B (padded)
    u16*   wa16s   = (u16*)(ws + 65536);      // 512 KB
    float* pms     = (float*)(ws + 589824);   // 16 KB (2048 x {max,sum})
    float* po      = (float*)(ws + 606208);   // 8 MB  (2048 x 1024 partial sums)

    k_prep<<<dim3(289), dim3(256), 0, stream>>>(enc, Ua_w, Ua_b, Wa_w, v_w,
                                                enc_out, wa16s, vsum);
    k_fused<<<dim3(B_ * NCH_), dim3(512), 0, stream>>>(dec, masks, enc_out, v_w, vsum,
                                                       wa16s, po, pms);
    k_comb<<<dim3(B_), dim3(256), 0, stream>>>(po, pms, out);
}